// Round 12
// baseline (174.450 us; speedup 1.0000x reference)
//
#include <hip/hip_runtime.h>

// CrossAttention restructured:  out = x @ ((G/qs) @ W^T) + b,  G = F^T F
//   F[m,d] = exp(x2[m,d]) * rsqrt(rowsum(exp));  qs = colsum(exp)
// R12: pass4 -> BM=32 x BN=512 tiles (x read ONCE; Mt L2-resident);
//      pass2 split-K partials in bf16 (R10-proven accuracy-safe, halves traffic).

typedef __attribute__((ext_vector_type(8))) short          s16x8;
typedef __attribute__((ext_vector_type(8))) unsigned short u16x8;
typedef __attribute__((ext_vector_type(4))) float          f32x4;

#define B_ 8
#define N_ 2048
#define D_ 512

__device__ inline unsigned short f2bf(float f) {  // f32 -> bf16 RNE
    unsigned u = __float_as_uint(f);
    u += 0x7FFFu + ((u >> 16) & 1u);
    return (unsigned short)(u >> 16);
}
__device__ inline float bf2f(unsigned short u) {
    return __uint_as_float((unsigned)u << 16);
}

// ---------- one-pass softmax: x2 read once -> Ft (bf16 [d][m], scaled), qs col sums ----------
__global__ __launch_bounds__(256) void softmax_fused_k(const float* __restrict__ x2,
                                                       unsigned short* __restrict__ Ft,
                                                       float* __restrict__ qs) {
    __shared__ unsigned short ft[32][522];
    __shared__ float cp[4][512];
    int b = blockIdx.y, m0 = blockIdx.x * 32;
    int w = threadIdx.x >> 6, l = threadIdx.x & 63;
    const int c0 = l * 8;
    float colacc[8] = {0.f, 0.f, 0.f, 0.f, 0.f, 0.f, 0.f, 0.f};
#pragma unroll
    for (int it = 0; it < 8; ++it) {
        int row = w * 8 + it;
        const float* p = x2 + ((size_t)b * N_ + m0 + row) * D_ + c0;
        float4 a = *(const float4*)p;
        float4 bb = *(const float4*)(p + 4);
        float e0 = __expf(a.x), e1 = __expf(a.y), e2 = __expf(a.z), e3 = __expf(a.w);
        float e4 = __expf(bb.x), e5 = __expf(bb.y), e6 = __expf(bb.z), e7 = __expf(bb.w);
        float s = e0 + e1 + e2 + e3 + e4 + e5 + e6 + e7;
#pragma unroll
        for (int off = 1; off < 64; off <<= 1) s += __shfl_xor(s, off);
        float rv = rsqrtf(s);
        u16x8 o;
        o[0] = f2bf(e0 * rv); o[1] = f2bf(e1 * rv); o[2] = f2bf(e2 * rv); o[3] = f2bf(e3 * rv);
        o[4] = f2bf(e4 * rv); o[5] = f2bf(e5 * rv); o[6] = f2bf(e6 * rv); o[7] = f2bf(e7 * rv);
        *(u16x8*)&ft[row][c0] = o;
        colacc[0] += e0; colacc[1] += e1; colacc[2] += e2; colacc[3] += e3;
        colacc[4] += e4; colacc[5] += e5; colacc[6] += e6; colacc[7] += e7;
    }
#pragma unroll
    for (int c = 0; c < 8; ++c) cp[w][c0 + c] = colacc[c];
    __syncthreads();
    for (int c = threadIdx.x; c < 512; c += 256) {
        float s = cp[0][c] + cp[1][c] + cp[2][c] + cp[3][c];
        atomicAdd(&qs[b * D_ + c], s);
    }
    int ml = l & 3, dr = l >> 2;
#pragma unroll
    for (int it = 0; it < 8; ++it) {
        int d = w * 128 + it * 16 + dr;
        u16x8 o;
#pragma unroll
        for (int k = 0; k < 8; ++k) o[k] = ft[ml * 8 + k][d];
        *(u16x8*)(Ft + ((size_t)b * D_ + d) * N_ + m0 + ml * 8) = o;
    }
}

// ---------- f32 -> bf16 bulk convert (W only) ----------
__global__ __launch_bounds__(256) void cvt_bf16_k(const float* __restrict__ in,
                                                  unsigned short* __restrict__ out) {
    size_t i = ((size_t)blockIdx.x * 256 + threadIdx.x) * 8;
    float4 a = *(const float4*)(in + i);
    float4 b = *(const float4*)(in + i + 4);
    u16x8 o;
    o[0] = f2bf(a.x); o[1] = f2bf(a.y); o[2] = f2bf(a.z); o[3] = f2bf(a.w);
    o[4] = f2bf(b.x); o[5] = f2bf(b.y); o[6] = f2bf(b.z); o[7] = f2bf(b.w);
    *(u16x8*)(out + i) = o;
}

// ---------- KQb[b][i][j] = bf16(sum_s Pbf[b,s][i][j] / qs[b][j]) ----------
__global__ __launch_bounds__(256) void cvt_kq_k(const unsigned short* __restrict__ Pbf,
                                                const float* __restrict__ qs,
                                                unsigned short* __restrict__ KQb) {
    size_t o = ((size_t)blockIdx.x * 256 + threadIdx.x) * 8;   // over B*512*512
    int b = (int)(o >> 18);
    size_t off = o & 262143;
    int j0 = (int)(o & 511);
    const unsigned short* base = Pbf + (size_t)b * 4 * 262144 + off;
    float sm[8] = {0.f, 0.f, 0.f, 0.f, 0.f, 0.f, 0.f, 0.f};
#pragma unroll
    for (int s = 0; s < 4; ++s) {
        u16x8 v = *(const u16x8*)(base + (size_t)s * 262144);
#pragma unroll
        for (int k = 0; k < 8; ++k) sm[k] += bf2f(v[k]);
    }
    float4 q0 = *(const float4*)(qs + b * D_ + j0);
    float4 q1 = *(const float4*)(qs + b * D_ + j0 + 4);
    u16x8 r;
    r[0] = f2bf(sm[0] / q0.x); r[1] = f2bf(sm[1] / q0.y);
    r[2] = f2bf(sm[2] / q0.z); r[3] = f2bf(sm[3] / q0.w);
    r[4] = f2bf(sm[4] / q1.x); r[5] = f2bf(sm[5] / q1.y);
    r[6] = f2bf(sm[6] / q1.z); r[7] = f2bf(sm[7] / q1.w);
    *(u16x8*)(KQb + o) = r;
}

__device__ inline void gload16(const unsigned short* g, unsigned short* l) {
    __builtin_amdgcn_global_load_lds((const __attribute__((address_space(1))) void*)g,
                                     (__attribute__((address_space(3))) void*)l, 16, 0, 0);
}
__device__ inline void gload16f(const float* g, float* l) {
    __builtin_amdgcn_global_load_lds((const __attribute__((address_space(1))) void*)g,
                                     (__attribute__((address_space(3))) void*)l, 16, 0, 0);
}

// ---------- pass 2 (SYRK): 128^2 tiles, split-K=4, bf16 partials Pbf[z][512][512] ----------
__global__ __launch_bounds__(256, 2) void gemm128_p2_k(const unsigned short* __restrict__ Ft,
                                                       unsigned short* __restrict__ Pbf) {
    __shared__ unsigned short As[128 * 32], Bs[128 * 32];
    const int K = N_;
    int z = blockIdx.z, b = z >> 2, ks = z & 3;
    int k0 = ks * 512;
    const unsigned short* Ab = Ft + (size_t)b * ((size_t)D_ * N_);
    int tid = threadIdx.x, w = tid >> 6, l = tid & 63;
    int wr = w >> 1, wc = w & 1;
    int lr = l & 15, lg = l >> 4;

    f32x4 acc[4][4];
#pragma unroll
    for (int i = 0; i < 4; ++i)
#pragma unroll
        for (int j = 0; j < 4; ++j) acc[i][j] = (f32x4){0.f, 0.f, 0.f, 0.f};

    const int rowbase = blockIdx.y * 128, colbase = blockIdx.x * 128;

    for (int kt = k0; kt < k0 + 512; kt += 32) {
#pragma unroll
        for (int i = 0; i < 2; ++i) {
            int ci = (i * 4 + w) * 64 + l;
            int row = ci >> 2, cc = ci & 3;
            gload16(Ab + (size_t)(rowbase + row) * K + kt + cc * 8, As + (i * 4 + w) * 512);
            gload16(Ab + (size_t)(colbase + row) * K + kt + cc * 8, Bs + (i * 4 + w) * 512);
        }
        __syncthreads();
        s16x8 af[4], bf[4];
#pragma unroll
        for (int i = 0; i < 4; ++i)
            af[i] = *(const s16x8*)&As[(wr * 64 + i * 16 + lr) * 32 + lg * 8];
#pragma unroll
        for (int j = 0; j < 4; ++j)
            bf[j] = *(const s16x8*)&Bs[(wc * 64 + j * 16 + lr) * 32 + lg * 8];
#pragma unroll
        for (int i = 0; i < 4; ++i)
#pragma unroll
            for (int j = 0; j < 4; ++j)
                acc[i][j] = __builtin_amdgcn_mfma_f32_16x16x32_bf16(af[i], bf[j], acc[i][j], 0, 0, 0);
        __syncthreads();
    }

    unsigned short* C = Pbf + (size_t)z * 262144;
#pragma unroll
    for (int i = 0; i < 4; ++i)
#pragma unroll
        for (int j = 0; j < 4; ++j) {
            int col = colbase + wc * 64 + j * 16 + lr;
#pragma unroll
            for (int r = 0; r < 4; ++r) {
                int row = rowbase + wr * 64 + i * 16 + lg * 4 + r;
                C[(size_t)row * D_ + col] = f2bf(acc[i][j][r]);
            }
        }
}

// ---------- pass 3: 64x64 tiles. Mt[e][i] = sum_j Wb[e][j]*KQb[i][j], bf16 out ----------
__global__ __launch_bounds__(256, 4) void gemm64_k(const unsigned short* __restrict__ A,
                                                   const unsigned short* __restrict__ Bm,
                                                   unsigned short* __restrict__ Cv,
                                                   int K, long long sA, long long sB, long long sC) {
    __shared__ unsigned short As[64 * 32], Bs[64 * 32];
    int b = blockIdx.z;
    const unsigned short* Ab = A + (size_t)b * sA;
    const unsigned short* Bb = Bm + (size_t)b * sB;
    int tid = threadIdx.x, w = tid >> 6, l = tid & 63;
    int wr = w >> 1, wc = w & 1;
    int lr = l & 15, lg = l >> 4;
    int srow = tid >> 2, scc = tid & 3;

    f32x4 acc[2][2];
#pragma unroll
    for (int i = 0; i < 2; ++i)
#pragma unroll
        for (int j = 0; j < 2; ++j) acc[i][j] = (f32x4){0.f, 0.f, 0.f, 0.f};

    const int rowbase = blockIdx.y * 64, colbase = blockIdx.x * 64;

    for (int kt = 0; kt < K; kt += 32) {
        gload16(Ab + (size_t)(rowbase + srow) * K + kt + scc * 8, As + w * 512);
        gload16(Bb + (size_t)(colbase + srow) * K + kt + scc * 8, Bs + w * 512);
        __syncthreads();
        s16x8 af[2], bf[2];
#pragma unroll
        for (int i = 0; i < 2; ++i)
            af[i] = *(const s16x8*)&As[(wr * 32 + i * 16 + lr) * 32 + lg * 8];
#pragma unroll
        for (int j = 0; j < 2; ++j)
            bf[j] = *(const s16x8*)&Bs[(wc * 32 + j * 16 + lr) * 32 + lg * 8];
#pragma unroll
        for (int i = 0; i < 2; ++i)
#pragma unroll
            for (int j = 0; j < 2; ++j)
                acc[i][j] = __builtin_amdgcn_mfma_f32_16x16x32_bf16(af[i], bf[j], acc[i][j], 0, 0, 0);
        __syncthreads();
    }

    unsigned short* C = Cv + (size_t)b * sC;
#pragma unroll
    for (int i = 0; i < 2; ++i)
#pragma unroll
        for (int j = 0; j < 2; ++j) {
            int col = colbase + wc * 32 + j * 16 + lr;
#pragma unroll
            for (int r = 0; r < 4; ++r) {
                int row = rowbase + wr * 32 + i * 16 + lg * 4 + r;
                C[(size_t)row * D_ + col] = f2bf(acc[i][j][r]);
            }
        }
}

// ---------- pass 4: BM=32 x BN=512 — x read ONCE, Mt from L2 ----------
// grid (64, B); wave w owns cols [w*128, w*128+128); acc[2][8].
__global__ __launch_bounds__(256, 2) void gemm_x512_k(const float* __restrict__ X,
                                                      const unsigned short* __restrict__ Bm,
                                                      float* __restrict__ Out,
                                                      const float* __restrict__ bias) {
    __shared__ float Asf[32 * 32];            // 4 KB
    __shared__ unsigned short Bs[512 * 32];   // 32 KB
    int b = blockIdx.y;
    const float* Ab = X + (size_t)b * ((size_t)N_ * D_);
    const unsigned short* Bb = Bm + (size_t)b * ((size_t)D_ * D_);
    int tid = threadIdx.x, w = tid >> 6, l = tid & 63;
    int lr = l & 15, lg = l >> 4;

    f32x4 acc[2][8];
#pragma unroll
    for (int i = 0; i < 2; ++i)
#pragma unroll
        for (int j = 0; j < 8; ++j) acc[i][j] = (f32x4){0.f, 0.f, 0.f, 0.f};

    const int rowbase = blockIdx.x * 32;

    for (int kt = 0; kt < D_; kt += 32) {
        // A (f32): 32 rows x 32 k = 4 KB -> 1 chunk/thread; dest = tid*16B (linear)
        gload16f(Ab + (size_t)(rowbase + (tid >> 3)) * D_ + kt + (tid & 7) * 4,
                 Asf + (size_t)tid * 4);
        // B (bf16): 512 rows x 32 k = 32 KB -> 8 chunks/thread
#pragma unroll
        for (int i = 0; i < 8; ++i) {
            int ci = i * 256 + tid;
            gload16(Bb + (size_t)(ci >> 2) * D_ + kt + (ci & 3) * 8, Bs + (size_t)ci * 8);
        }
        __syncthreads();
        s16x8 af[2], bf[8];
#pragma unroll
        for (int i = 0; i < 2; ++i) {
            const float* ap = &Asf[(i * 16 + lr) * 32 + lg * 8];
            f32x4 a0 = *(const f32x4*)ap, a1 = *(const f32x4*)(ap + 4);
            s16x8 t;
            t[0] = (short)f2bf(a0[0]); t[1] = (short)f2bf(a0[1]);
            t[2] = (short)f2bf(a0[2]); t[3] = (short)f2bf(a0[3]);
            t[4] = (short)f2bf(a1[0]); t[5] = (short)f2bf(a1[1]);
            t[6] = (short)f2bf(a1[2]); t[7] = (short)f2bf(a1[3]);
            af[i] = t;
        }
#pragma unroll
        for (int j = 0; j < 8; ++j)
            bf[j] = *(const s16x8*)&Bs[(w * 128 + j * 16 + lr) * 32 + lg * 8];
#pragma unroll
        for (int i = 0; i < 2; ++i)
#pragma unroll
            for (int j = 0; j < 8; ++j)
                acc[i][j] = __builtin_amdgcn_mfma_f32_16x16x32_bf16(af[i], bf[j], acc[i][j], 0, 0, 0);
        __syncthreads();
    }

    float* C = Out + (size_t)b * ((size_t)N_ * D_);
#pragma unroll
    for (int i = 0; i < 2; ++i)
#pragma unroll
        for (int j = 0; j < 8; ++j) {
            int col = w * 128 + j * 16 + lr;
            float bv = bias[col];
#pragma unroll
            for (int r = 0; r < 4; ++r) {
                int row = rowbase + i * 16 + lg * 4 + r;
                C[(size_t)row * D_ + col] = acc[i][j][r] + bv;
            }
        }
}

extern "C" void kernel_launch(void* const* d_in, const int* in_sizes, int n_in,
                              void* d_out, int out_size, void* d_ws, size_t ws_size,
                              hipStream_t stream) {
    const float* x    = (const float*)d_in[0];   // [8,2048,512]
    const float* x2   = (const float*)d_in[1];   // [8,2048,512]
    const float* W    = (const float*)d_in[2];   // [512,512]
    const float* bias = (const float*)d_in[3];   // [512]
    float* out = (float*)d_out;                  // [8,2048,512] f32

    // workspace carve — ~59 MB
    unsigned short* Ft  = (unsigned short*)d_ws;         // [8][512][2048] bf16
    unsigned short* Wb  = Ft + 8388608;                  // [512][512]
    unsigned short* KQb = Wb + 262144;                   // [8][512][512] bf16
    unsigned short* Mt  = KQb + 2097152;                 // [8][512][512] bf16
    unsigned short* Pbf = Mt + 2097152;                  // [8][4][512][512] bf16 split-K partials
    float* qs = (float*)(Pbf + 8388608);                 // [8*512]

    hipMemsetAsync(qs, 0, (size_t)B_ * D_ * sizeof(float), stream);

    // one-pass softmax: x2 read once -> Ft (scaled, transposed), qs
    softmax_fused_k<<<dim3(N_ / 32, B_), 256, 0, stream>>>(x2, Ft, qs);

    // bf16 W
    cvt_bf16_k<<<dim3(128), 256, 0, stream>>>(W, Wb);

    // pass 2 (SYRK): Pbf[b,ks] = Ft-rows . Ft-cols^T over quarter-K each (128^2 tiles)
    gemm128_p2_k<<<dim3(4, 4, B_ * 4), 256, 0, stream>>>(Ft, Pbf);

    // KQ = (sum_s Pbf)/qs -> bf16
    cvt_kq_k<<<dim3(1024), 256, 0, stream>>>(Pbf, qs, KQb);

    // pass 3: Mt[e][i] = sum_j Wb[e][j]*KQb[i][j]
    gemm64_k<<<dim3(8, 8, B_), 256, 0, stream>>>(
        Wb, KQb, Mt, 512, 0LL, (long long)512 * 512, (long long)512 * 512);

    // pass 4: out[n][e] = sum_i x[n][i]*Mt[e][i] + b[e]  (BM=32 x BN=512, x read once)
    gemm_x512_k<<<dim3(N_ / 32, B_), 256, 0, stream>>>(x, Mt, out, bias);
}

// Round 13
// 167.001 us; speedup vs baseline: 1.0446x; 1.0446x over previous
//
#include <hip/hip_runtime.h>

// CrossAttention restructured:  out = x @ ((G/qs) @ W^T) + b,  G = F^T F
//   F[m,d] = exp(x2[m,d]) * rsqrt(rowsum(exp));  qs = colsum(exp)
// R13: revert pass4 to R11's 128x128 gemm_xf32_k (R12's BM=32xBN=512 was
//      latency-bound: x re-reads were L3-absorbed all along, FETCH proved it).
//      Keep R12's bf16 split-K partials (accuracy proven, halves traffic).

typedef __attribute__((ext_vector_type(8))) short          s16x8;
typedef __attribute__((ext_vector_type(8))) unsigned short u16x8;
typedef __attribute__((ext_vector_type(4))) float          f32x4;

#define B_ 8
#define N_ 2048
#define D_ 512

__device__ inline unsigned short f2bf(float f) {  // f32 -> bf16 RNE
    unsigned u = __float_as_uint(f);
    u += 0x7FFFu + ((u >> 16) & 1u);
    return (unsigned short)(u >> 16);
}
__device__ inline float bf2f(unsigned short u) {
    return __uint_as_float((unsigned)u << 16);
}

// ---------- one-pass softmax: x2 read once -> Ft (bf16 [d][m], scaled), qs col sums ----------
__global__ __launch_bounds__(256) void softmax_fused_k(const float* __restrict__ x2,
                                                       unsigned short* __restrict__ Ft,
                                                       float* __restrict__ qs) {
    __shared__ unsigned short ft[32][522];
    __shared__ float cp[4][512];
    int b = blockIdx.y, m0 = blockIdx.x * 32;
    int w = threadIdx.x >> 6, l = threadIdx.x & 63;
    const int c0 = l * 8;
    float colacc[8] = {0.f, 0.f, 0.f, 0.f, 0.f, 0.f, 0.f, 0.f};
#pragma unroll
    for (int it = 0; it < 8; ++it) {
        int row = w * 8 + it;
        const float* p = x2 + ((size_t)b * N_ + m0 + row) * D_ + c0;
        float4 a = *(const float4*)p;
        float4 bb = *(const float4*)(p + 4);
        float e0 = __expf(a.x), e1 = __expf(a.y), e2 = __expf(a.z), e3 = __expf(a.w);
        float e4 = __expf(bb.x), e5 = __expf(bb.y), e6 = __expf(bb.z), e7 = __expf(bb.w);
        float s = e0 + e1 + e2 + e3 + e4 + e5 + e6 + e7;
#pragma unroll
        for (int off = 1; off < 64; off <<= 1) s += __shfl_xor(s, off);
        float rv = rsqrtf(s);
        u16x8 o;
        o[0] = f2bf(e0 * rv); o[1] = f2bf(e1 * rv); o[2] = f2bf(e2 * rv); o[3] = f2bf(e3 * rv);
        o[4] = f2bf(e4 * rv); o[5] = f2bf(e5 * rv); o[6] = f2bf(e6 * rv); o[7] = f2bf(e7 * rv);
        *(u16x8*)&ft[row][c0] = o;
        colacc[0] += e0; colacc[1] += e1; colacc[2] += e2; colacc[3] += e3;
        colacc[4] += e4; colacc[5] += e5; colacc[6] += e6; colacc[7] += e7;
    }
#pragma unroll
    for (int c = 0; c < 8; ++c) cp[w][c0 + c] = colacc[c];
    __syncthreads();
    for (int c = threadIdx.x; c < 512; c += 256) {
        float s = cp[0][c] + cp[1][c] + cp[2][c] + cp[3][c];
        atomicAdd(&qs[b * D_ + c], s);
    }
    int ml = l & 3, dr = l >> 2;
#pragma unroll
    for (int it = 0; it < 8; ++it) {
        int d = w * 128 + it * 16 + dr;
        u16x8 o;
#pragma unroll
        for (int k = 0; k < 8; ++k) o[k] = ft[ml * 8 + k][d];
        *(u16x8*)(Ft + ((size_t)b * D_ + d) * N_ + m0 + ml * 8) = o;
    }
}

// ---------- f32 -> bf16 bulk convert (W only) ----------
__global__ __launch_bounds__(256) void cvt_bf16_k(const float* __restrict__ in,
                                                  unsigned short* __restrict__ out) {
    size_t i = ((size_t)blockIdx.x * 256 + threadIdx.x) * 8;
    float4 a = *(const float4*)(in + i);
    float4 b = *(const float4*)(in + i + 4);
    u16x8 o;
    o[0] = f2bf(a.x); o[1] = f2bf(a.y); o[2] = f2bf(a.z); o[3] = f2bf(a.w);
    o[4] = f2bf(b.x); o[5] = f2bf(b.y); o[6] = f2bf(b.z); o[7] = f2bf(b.w);
    *(u16x8*)(out + i) = o;
}

// ---------- KQb[b][i][j] = bf16(sum_s Pbf[b,s][i][j] / qs[b][j]) ----------
__global__ __launch_bounds__(256) void cvt_kq_k(const unsigned short* __restrict__ Pbf,
                                                const float* __restrict__ qs,
                                                unsigned short* __restrict__ KQb) {
    size_t o = ((size_t)blockIdx.x * 256 + threadIdx.x) * 8;   // over B*512*512
    int b = (int)(o >> 18);
    size_t off = o & 262143;
    int j0 = (int)(o & 511);
    const unsigned short* base = Pbf + (size_t)b * 4 * 262144 + off;
    float sm[8] = {0.f, 0.f, 0.f, 0.f, 0.f, 0.f, 0.f, 0.f};
#pragma unroll
    for (int s = 0; s < 4; ++s) {
        u16x8 v = *(const u16x8*)(base + (size_t)s * 262144);
#pragma unroll
        for (int k = 0; k < 8; ++k) sm[k] += bf2f(v[k]);
    }
    float4 q0 = *(const float4*)(qs + b * D_ + j0);
    float4 q1 = *(const float4*)(qs + b * D_ + j0 + 4);
    u16x8 r;
    r[0] = f2bf(sm[0] / q0.x); r[1] = f2bf(sm[1] / q0.y);
    r[2] = f2bf(sm[2] / q0.z); r[3] = f2bf(sm[3] / q0.w);
    r[4] = f2bf(sm[4] / q1.x); r[5] = f2bf(sm[5] / q1.y);
    r[6] = f2bf(sm[6] / q1.z); r[7] = f2bf(sm[7] / q1.w);
    *(u16x8*)(KQb + o) = r;
}

__device__ inline void gload16(const unsigned short* g, unsigned short* l) {
    __builtin_amdgcn_global_load_lds((const __attribute__((address_space(1))) void*)g,
                                     (__attribute__((address_space(3))) void*)l, 16, 0, 0);
}
__device__ inline void gload16f(const float* g, float* l) {
    __builtin_amdgcn_global_load_lds((const __attribute__((address_space(1))) void*)g,
                                     (__attribute__((address_space(3))) void*)l, 16, 0, 0);
}

// ---------- pass 2 (SYRK): 128^2 tiles, split-K=4, bf16 partials Pbf[z][512][512] ----------
__global__ __launch_bounds__(256, 2) void gemm128_p2_k(const unsigned short* __restrict__ Ft,
                                                       unsigned short* __restrict__ Pbf) {
    __shared__ unsigned short As[128 * 32], Bs[128 * 32];
    const int K = N_;
    int z = blockIdx.z, b = z >> 2, ks = z & 3;
    int k0 = ks * 512;
    const unsigned short* Ab = Ft + (size_t)b * ((size_t)D_ * N_);
    int tid = threadIdx.x, w = tid >> 6, l = tid & 63;
    int wr = w >> 1, wc = w & 1;
    int lr = l & 15, lg = l >> 4;

    f32x4 acc[4][4];
#pragma unroll
    for (int i = 0; i < 4; ++i)
#pragma unroll
        for (int j = 0; j < 4; ++j) acc[i][j] = (f32x4){0.f, 0.f, 0.f, 0.f};

    const int rowbase = blockIdx.y * 128, colbase = blockIdx.x * 128;

    for (int kt = k0; kt < k0 + 512; kt += 32) {
#pragma unroll
        for (int i = 0; i < 2; ++i) {
            int ci = (i * 4 + w) * 64 + l;
            int row = ci >> 2, cc = ci & 3;
            gload16(Ab + (size_t)(rowbase + row) * K + kt + cc * 8, As + (i * 4 + w) * 512);
            gload16(Ab + (size_t)(colbase + row) * K + kt + cc * 8, Bs + (i * 4 + w) * 512);
        }
        __syncthreads();
        s16x8 af[4], bf[4];
#pragma unroll
        for (int i = 0; i < 4; ++i)
            af[i] = *(const s16x8*)&As[(wr * 64 + i * 16 + lr) * 32 + lg * 8];
#pragma unroll
        for (int j = 0; j < 4; ++j)
            bf[j] = *(const s16x8*)&Bs[(wc * 64 + j * 16 + lr) * 32 + lg * 8];
#pragma unroll
        for (int i = 0; i < 4; ++i)
#pragma unroll
            for (int j = 0; j < 4; ++j)
                acc[i][j] = __builtin_amdgcn_mfma_f32_16x16x32_bf16(af[i], bf[j], acc[i][j], 0, 0, 0);
        __syncthreads();
    }

    unsigned short* C = Pbf + (size_t)z * 262144;
#pragma unroll
    for (int i = 0; i < 4; ++i)
#pragma unroll
        for (int j = 0; j < 4; ++j) {
            int col = colbase + wc * 64 + j * 16 + lr;
#pragma unroll
            for (int r = 0; r < 4; ++r) {
                int row = rowbase + wr * 64 + i * 16 + lg * 4 + r;
                C[(size_t)row * D_ + col] = f2bf(acc[i][j][r]);
            }
        }
}

// ---------- pass 3: 64x64 tiles. Mt[e][i] = sum_j Wb[e][j]*KQb[i][j], bf16 out ----------
__global__ __launch_bounds__(256, 4) void gemm64_k(const unsigned short* __restrict__ A,
                                                   const unsigned short* __restrict__ Bm,
                                                   unsigned short* __restrict__ Cv,
                                                   int K, long long sA, long long sB, long long sC) {
    __shared__ unsigned short As[64 * 32], Bs[64 * 32];
    int b = blockIdx.z;
    const unsigned short* Ab = A + (size_t)b * sA;
    const unsigned short* Bb = Bm + (size_t)b * sB;
    int tid = threadIdx.x, w = tid >> 6, l = tid & 63;
    int wr = w >> 1, wc = w & 1;
    int lr = l & 15, lg = l >> 4;
    int srow = tid >> 2, scc = tid & 3;

    f32x4 acc[2][2];
#pragma unroll
    for (int i = 0; i < 2; ++i)
#pragma unroll
        for (int j = 0; j < 2; ++j) acc[i][j] = (f32x4){0.f, 0.f, 0.f, 0.f};

    const int rowbase = blockIdx.y * 64, colbase = blockIdx.x * 64;

    for (int kt = 0; kt < K; kt += 32) {
        gload16(Ab + (size_t)(rowbase + srow) * K + kt + scc * 8, As + w * 512);
        gload16(Bb + (size_t)(colbase + srow) * K + kt + scc * 8, Bs + w * 512);
        __syncthreads();
        s16x8 af[2], bf[2];
#pragma unroll
        for (int i = 0; i < 2; ++i)
            af[i] = *(const s16x8*)&As[(wr * 32 + i * 16 + lr) * 32 + lg * 8];
#pragma unroll
        for (int j = 0; j < 2; ++j)
            bf[j] = *(const s16x8*)&Bs[(wc * 32 + j * 16 + lr) * 32 + lg * 8];
#pragma unroll
        for (int i = 0; i < 2; ++i)
#pragma unroll
            for (int j = 0; j < 2; ++j)
                acc[i][j] = __builtin_amdgcn_mfma_f32_16x16x32_bf16(af[i], bf[j], acc[i][j], 0, 0, 0);
        __syncthreads();
    }

    unsigned short* C = Cv + (size_t)b * sC;
#pragma unroll
    for (int i = 0; i < 2; ++i)
#pragma unroll
        for (int j = 0; j < 2; ++j) {
            int col = colbase + wc * 32 + j * 16 + lr;
#pragma unroll
            for (int r = 0; r < 4; ++r) {
                int row = rowbase + wr * 32 + i * 16 + lg * 4 + r;
                C[(size_t)row * D_ + col] = f2bf(acc[i][j][r]);
            }
        }
}

// ---------- pass 4: out = x(f32, staged+cvt in-kernel) @ Mt^T + bias (128x128) ----------
__global__ __launch_bounds__(256, 2) void gemm_xf32_k(const float* __restrict__ X,
                                                      const unsigned short* __restrict__ Bm,
                                                      float* __restrict__ Out,
                                                      const float* __restrict__ bias) {
    __shared__ float Asf[128 * 32];
    __shared__ unsigned short Bs[128 * 32];
    int b = blockIdx.z;
    const float* Ab = X + (size_t)b * ((size_t)N_ * D_);
    const unsigned short* Bb = Bm + (size_t)b * ((size_t)D_ * D_);
    int tm = blockIdx.y, tn = blockIdx.x;
    int tid = threadIdx.x, w = tid >> 6, l = tid & 63;
    int wr = w >> 1, wc = w & 1;
    int lr = l & 15, lg = l >> 4;

    f32x4 acc[4][4];
#pragma unroll
    for (int i = 0; i < 4; ++i)
#pragma unroll
        for (int j = 0; j < 4; ++j) acc[i][j] = (f32x4){0.f, 0.f, 0.f, 0.f};

    const int rowbase = tm * 128, colbase = tn * 128;

    for (int kt = 0; kt < D_; kt += 32) {
#pragma unroll
        for (int i = 0; i < 4; ++i) {
            int ci = (i * 4 + w) * 64 + l;
            int row = ci >> 3, cc = ci & 7;
            gload16f(Ab + (size_t)(rowbase + row) * D_ + kt + cc * 4, Asf + (i * 4 + w) * 256);
        }
#pragma unroll
        for (int i = 0; i < 2; ++i) {
            int ci = (i * 4 + w) * 64 + l;
            int row = ci >> 2, cc = ci & 3;
            gload16(Bb + (size_t)(colbase + row) * D_ + kt + cc * 8, Bs + (i * 4 + w) * 512);
        }
        __syncthreads();
        s16x8 af[4], bf[4];
#pragma unroll
        for (int i = 0; i < 4; ++i) {
            const float* ap = &Asf[(wr * 64 + i * 16 + lr) * 32 + lg * 8];
            f32x4 a0 = *(const f32x4*)ap, a1 = *(const f32x4*)(ap + 4);
            s16x8 t;
            t[0] = (short)f2bf(a0[0]); t[1] = (short)f2bf(a0[1]);
            t[2] = (short)f2bf(a0[2]); t[3] = (short)f2bf(a0[3]);
            t[4] = (short)f2bf(a1[0]); t[5] = (short)f2bf(a1[1]);
            t[6] = (short)f2bf(a1[2]); t[7] = (short)f2bf(a1[3]);
            af[i] = t;
        }
#pragma unroll
        for (int j = 0; j < 4; ++j)
            bf[j] = *(const s16x8*)&Bs[(wc * 64 + j * 16 + lr) * 32 + lg * 8];
#pragma unroll
        for (int i = 0; i < 4; ++i)
#pragma unroll
            for (int j = 0; j < 4; ++j)
                acc[i][j] = __builtin_amdgcn_mfma_f32_16x16x32_bf16(af[i], bf[j], acc[i][j], 0, 0, 0);
        __syncthreads();
    }

    float* C = Out + (size_t)b * ((size_t)N_ * D_);
#pragma unroll
    for (int i = 0; i < 4; ++i)
#pragma unroll
        for (int j = 0; j < 4; ++j) {
            int col = colbase + wc * 64 + j * 16 + lr;
            float bv = bias[col];
#pragma unroll
            for (int r = 0; r < 4; ++r) {
                int row = rowbase + wr * 64 + i * 16 + lg * 4 + r;
                C[(size_t)row * D_ + col] = acc[i][j][r] + bv;
            }
        }
}

extern "C" void kernel_launch(void* const* d_in, const int* in_sizes, int n_in,
                              void* d_out, int out_size, void* d_ws, size_t ws_size,
                              hipStream_t stream) {
    const float* x    = (const float*)d_in[0];   // [8,2048,512]
    const float* x2   = (const float*)d_in[1];   // [8,2048,512]
    const float* W    = (const float*)d_in[2];   // [512,512]
    const float* bias = (const float*)d_in[3];   // [512]
    float* out = (float*)d_out;                  // [8,2048,512] f32

    // workspace carve — ~43 MB
    unsigned short* Ft  = (unsigned short*)d_ws;         // [8][512][2048] bf16
    unsigned short* Wb  = Ft + 8388608;                  // [512][512]
    unsigned short* KQb = Wb + 262144;                   // [8][512][512] bf16
    unsigned short* Mt  = KQb + 2097152;                 // [8][512][512] bf16
    unsigned short* Pbf = Mt + 2097152;                  // [8][4][512][512] bf16 split-K partials
    float* qs = (float*)(Pbf + 8388608);                 // [8*512]

    hipMemsetAsync(qs, 0, (size_t)B_ * D_ * sizeof(float), stream);

    // one-pass softmax: x2 read once -> Ft (scaled, transposed), qs
    softmax_fused_k<<<dim3(N_ / 32, B_), 256, 0, stream>>>(x2, Ft, qs);

    // bf16 W
    cvt_bf16_k<<<dim3(128), 256, 0, stream>>>(W, Wb);

    // pass 2 (SYRK): Pbf[b,ks] = Ft-rows . Ft-cols^T over quarter-K each (128^2 tiles)
    gemm128_p2_k<<<dim3(4, 4, B_ * 4), 256, 0, stream>>>(Ft, Pbf);

    // KQ = (sum_s Pbf)/qs -> bf16
    cvt_kq_k<<<dim3(1024), 256, 0, stream>>>(Pbf, qs, KQb);

    // pass 3: Mt[e][i] = sum_j Wb[e][j]*KQb[i][j]
    gemm64_k<<<dim3(8, 8, B_), 256, 0, stream>>>(
        Wb, KQb, Mt, 512, 0LL, (long long)512 * 512, (long long)512 * 512);

    // pass 4: out[n][e] = sum_i x[n][i]*Mt[e][i] + b[e]  (f32 A staged in-kernel)
    gemm_xf32_k<<<dim3(4, 16, B_), 256, 0, stream>>>(x, Mt, out, bias);
}